// Round 7
// baseline (444.427 us; speedup 1.0000x reference)
//
#include <hip/hip_runtime.h>
#include <hip/hip_bf16.h>
#include <math.h>

#define NB 8
#define NN 4096
#define KK 16
#define MM (NB*NN)
#define CH 32
#define SLOTS 17
#define NCLS 40
#define BIG 3.0e38f
#define CAP 324   // survivor list capacity; P(overflow) ~ 4e-4 over whole dataset

// Weight table offsets (floats)
#define OW1A 0
#define OB1A 128
#define OW1B 160
#define OB1B 1184
#define OW2A 1216
#define OB2A 2368
#define OW2B 2400
#define OB2B 3424
#define OWC  3456
#define OBC  4736
#define NWTS 4776

// Module-global scratch (~11 MB): no assumptions about ws_size.
__device__ float4 g_pos4[MM];
__device__ float4 g_nrm4[MM];
__device__ int    g_nbr[MM*KK];
__device__ float  g_u[MM*CH];
__device__ float  g_x2[MM*CH];
__device__ float  g_wts[NWTS];
__device__ int    g_isf32;

__device__ __forceinline__ float bf(const __hip_bfloat16 x) { return __bfloat162float(x); }

// dual-dtype load: element i of array that is either float32 or bf16
__device__ __forceinline__ float ldf(const void* p, int i, bool f32) {
  return f32 ? ((const float*)p)[i] : bf(((const __hip_bfloat16*)p)[i]);
}

__device__ __forceinline__ float angf(float ax, float ay, float az,
                                      float bx, float by, float bz) {
  float cx = ay*bz - az*by;
  float cy = az*bx - ax*bz;
  float cz = ax*by - ay*bx;
  float s  = cx*cx + cy*cy + cz*cz;
  float cn = s > 0.f ? sqrtf(s) : 0.f;
  float d  = ax*bx + ay*by + az*bz;
  return (cn > 0.f || d != 0.f) ? atan2f(cn, d) : 0.f;
}

__device__ __forceinline__ void ppf4(const float4 pi, const float4 ni,
                                     const float4 pj, const float4 nj, float* f) {
  float px = pj.x - pi.x, py = pj.y - pi.y, pz = pj.z - pi.z;
  float s = px*px + py*py + pz*pz;
  f[0] = s > 0.f ? sqrtf(s) : 0.f;
  f[1] = angf(ni.x, ni.y, ni.z, px, py, pz);
  f[2] = angf(nj.x, nj.y, nj.z, px, py, pz);
  f[3] = angf(ni.x, ni.y, ni.z, nj.x, nj.y, nj.z);
}

// ---------------- wprep: parallel dtype vote + convert weights to fp32 ----------------
__global__ __launch_bounds__(256) void wprep_kernel(
    const void* nrm, const void* w1a, const void* b1a, const void* w1b,
    const void* b1b, const void* w2a, const void* b2a, const void* w2b,
    const void* b2b, const void* wc, const void* bc) {
  __shared__ int sflag;
  const int tid = threadIdx.x;
  if (tid < 64) {
    // one lane per normal vector; normals are unit-norm under the TRUE dtype
    const float* nf = (const float*)nrm;
    const __hip_bfloat16* nh = (const __hip_bfloat16*)nrm;
    float x = nf[3*tid], y = nf[3*tid+1], z = nf[3*tid+2];
    float ss = x*x + y*y + z*z;
    bool okf = (ss > 0.98f && ss < 1.02f);
    float a = bf(nh[3*tid]), b2 = bf(nh[3*tid+1]), c2 = bf(nh[3*tid+2]);
    float sb = a*a + b2*b2 + c2*c2;
    bool okb = (sb > 0.95f && sb < 1.05f);
    unsigned long long mf = __ballot(okf), mb = __ballot(okb);
    if (tid == 0) {
      sflag = (__popcll(mf) >= __popcll(mb)) ? 1 : 0;
      g_isf32 = sflag;
    }
  }
  __syncthreads();
  const bool f32 = sflag != 0;
  for (int i = tid; i < 128;  i += 256) g_wts[OW1A + i] = ldf(w1a, i, f32);
  for (int i = tid; i < 32;   i += 256) g_wts[OB1A + i] = ldf(b1a, i, f32);
  for (int i = tid; i < 1024; i += 256) g_wts[OW1B + i] = ldf(w1b, i, f32);
  for (int i = tid; i < 32;   i += 256) g_wts[OB1B + i] = ldf(b1b, i, f32);
  for (int i = tid; i < 1152; i += 256) g_wts[OW2A + i] = ldf(w2a, i, f32);
  for (int i = tid; i < 32;   i += 256) g_wts[OB2A + i] = ldf(b2a, i, f32);
  for (int i = tid; i < 1024; i += 256) g_wts[OW2B + i] = ldf(w2b, i, f32);
  for (int i = tid; i < 32;   i += 256) g_wts[OB2B + i] = ldf(b2b, i, f32);
  for (int i = tid; i < 1280; i += 256) g_wts[OWC  + i] = ldf(wc,  i, f32);
  for (int i = tid; i < 40;   i += 256) g_wts[OBC  + i] = ldf(bc,  i, f32);
}

// ---------------- prep: inputs -> float4 (pos.w = |p|^2 f32, filter only) ----------------
__global__ __launch_bounds__(256) void prep_kernel(const void* __restrict__ pos,
                                                   const void* __restrict__ nrm) {
  const bool f32 = g_isf32 != 0;
  int i = blockIdx.x*256 + threadIdx.x;
  float x = ldf(pos, 3*i, f32), y = ldf(pos, 3*i+1, f32), z = ldf(pos, 3*i+2, f32);
  float sq = x*x + y*y + z*z;
  g_pos4[i] = make_float4(x, y, z, sq);
  float a = ldf(nrm, 3*i, f32), b = ldf(nrm, 3*i+1, f32), c = ldf(nrm, 3*i+2, f32);
  g_nrm4[i] = make_float4(a, b, c, 0.f);
}

// ---------------- kNN: one wave per point, f32 filter + f64 exact ranking ----------------
// f32 filter pass (expanded formula); threshold T = max over 16 residue classes
// of the class min => >=16 distinct candidates <= T. Inflated by absolute
// margin 2e-5 (+1e-5 rel) >> f32 d2 abs error, so every true top-16 survives.
// Survivors collected via ballot-prefix compaction (no atomics, wave-private
// register count). f64 rescore (numpy-exact association) from L2-hot g_pos4,
// then exact lexicographic (d2_f64, idx) ranking (= top_k tie-break).
// LDS 31.9 KB -> 5 blocks/CU (20 waves/CU), vs 48.5 KB (3 blocks) before.
__global__ __launch_bounds__(256) void knn_kernel() {
  __shared__ float4 tile[1024];        // 16384 B
  __shared__ int    ilst[4][CAP];      //  5184 B
  __shared__ double dlst[4][CAP];      // 10368 B
  const int tid  = threadIdx.x;
  const int w    = tid >> 6, lane = tid & 63;
  const int blk  = blockIdx.x;
  const int b    = blk >> 10;                 // 1024 blocks per batch
  const int pib  = ((blk & 1023) << 2) | w;   // point-in-batch
  const float4* bp = g_pos4 + b*NN;
  const float4 me = bp[pib];
  float d2c[64];
  float lmin = BIG;
  #pragma unroll
  for (int t = 0; t < 4; ++t) {
    #pragma unroll
    for (int k = 0; k < 4; ++k) tile[k*256 + tid] = bp[t*1024 + k*256 + tid];
    __syncthreads();
    #pragma unroll
    for (int r = 0; r < 16; ++r) {
      float4 o  = tile[r*64 + lane];
      int cand  = t*1024 + r*64 + lane;
      float dt  = me.x*o.x + me.y*o.y + me.z*o.z;
      float d2  = (me.w + o.w) - 2.f*dt;
      d2 = (cand == pib) ? BIG : d2;           // exclude self
      d2c[t*16 + r] = d2;
      lmin = fminf(lmin, d2);
    }
    __syncthreads();
  }
  // class = lane&15; merge lanes sharing a class (each class = 256 candidates)
  lmin = fminf(lmin, __shfl_xor(lmin, 16));
  lmin = fminf(lmin, __shfl_xor(lmin, 32));
  float T = lmin;
  #pragma unroll
  for (int d = 1; d < 64; d <<= 1) T = fmaxf(T, __shfl_xor(T, d));
  const float Tf = T + 2e-5f + 1e-5f*fabsf(T);  // absolute margin >> f32 d2 error

  // ballot-prefix compaction into wave-private list (no atomics)
  int cnt = 0;
  #pragma unroll
  for (int u0 = 0; u0 < 64; ++u0) {
    float d2 = d2c[u0];
    bool hit = d2 <= Tf;
    unsigned long long mask = __ballot(hit);
    if (hit) {
      int pos = cnt + __popcll(mask & ((1ull << lane) - 1ull));
      if (pos < CAP) {
        int cand = (u0 >> 4)*1024 + (u0 & 15)*64 + lane;
        ilst[w][pos] = cand;
      }
    }
    cnt += (int)__popcll(mask);
  }
  const int m = min(cnt, CAP);
  __syncthreads();
  // f64 re-score of survivors, numpy-exact association (positions from L2-hot global)
  const double mx = (double)me.x, my_ = (double)me.y, mz = (double)me.z;
  const double sqme = (mx*mx + my_*my_) + mz*mz;
  for (int e = lane; e < m; e += 64) {
    int ci = ilst[w][e];
    float4 o = bp[ci];
    double ox = (double)o.x, oy = (double)o.y, oz = (double)o.z;
    double sqo = (ox*ox + oy*oy) + oz*oz;
    double dt  = (mx*ox + my_*oy) + mz*oz;
    dlst[w][e] = (sqme + sqo) - 2.0*dt;
  }
  __syncthreads();
  for (int e = lane; e < m; e += 64) {
    double myd = dlst[w][e];
    int myi = ilst[w][e];
    int rank = 0;
    for (int o = 0; o < m; ++o) {            // broadcast LDS reads
      double od = dlst[w][o];
      int oi = ilst[w][o];
      rank += (od < myd) || (od == myd && oi < myi);
    }
    if (rank < KK) g_nbr[(b*NN + pib)*KK + rank] = b*NN + myi;
  }
}

// ---------------- conv1: 8 nodes/block, fused u = relu(max(msg1)) @ w2a[0:32] ----------------
__global__ __launch_bounds__(256) void conv1_kernel() {
  __shared__ __align__(16) float fe[136][4];
  __shared__ __align__(16) float h1s[8*SLOTS*CH];
  __shared__ __align__(16) float xs[8][CH];
  const int tid = threadIdx.x;
  const int c = tid & 31;
  const int node0 = blockIdx.x << 3;
  float w1a_c[4], w1b_c[32], w2a_c[32];
  #pragma unroll
  for (int f = 0; f < 4; ++f)  w1a_c[f] = g_wts[OW1A + f*CH + c];
  #pragma unroll
  for (int k = 0; k < 32; ++k) w1b_c[k] = g_wts[OW1B + k*CH + c];
  #pragma unroll
  for (int k = 0; k < 32; ++k) w2a_c[k] = g_wts[OW2A + k*CH + c];
  const float b1a_c = g_wts[OB1A + c], b1b_c = g_wts[OB1B + c];

  if (tid < 136) {
    int ns = tid / 17, slot = tid - ns*17;
    int i = node0 + ns;
    int j = (slot < KK) ? g_nbr[i*KK + slot] : i;   // slot 16 = self-loop
    ppf4(g_pos4[i], g_nrm4[i], g_pos4[j], g_nrm4[j], fe[tid]);
  }
  __syncthreads();
  #pragma unroll
  for (int it = 0; it < 17; ++it) {
    int idx = it*256 + tid;                   // (e, c) with c == tid&31
    int e = idx >> 5;
    float4 f4 = *(const float4*)fe[e];
    float h = b1a_c + f4.x*w1a_c[0] + f4.y*w1a_c[1] + f4.z*w1a_c[2] + f4.w*w1a_c[3];
    h1s[idx] = fmaxf(h, 0.f);
  }
  __syncthreads();
  const int ns = tid >> 5;
  const int i  = node0 + ns;
  float acc = -BIG;
  #pragma unroll
  for (int slot = 0; slot < SLOTS; ++slot) {
    const float* hr = &h1s[(ns*SLOTS + slot)*CH];
    float msg = b1b_c;
    #pragma unroll
    for (int k4 = 0; k4 < 8; ++k4) {
      float4 h4 = *(const float4*)(hr + 4*k4);
      msg += h4.x*w1b_c[4*k4] + h4.y*w1b_c[4*k4+1] + h4.z*w1b_c[4*k4+2] + h4.w*w1b_c[4*k4+3];
    }
    acc = fmaxf(acc, msg);
  }
  xs[ns][c] = fmaxf(acc, 0.f);                // x1 = relu(segment_max)
  __syncthreads();
  float uu = 0.f;
  #pragma unroll
  for (int k4 = 0; k4 < 8; ++k4) {
    float4 x4 = *(const float4*)&xs[ns][4*k4];
    uu += x4.x*w2a_c[4*k4] + x4.y*w2a_c[4*k4+1] + x4.z*w2a_c[4*k4+2] + x4.w*w2a_c[4*k4+3];
  }
  g_u[i*CH + c] = uu;                         // u = x1 @ w2a[0:32,:]
}

// ---------------- conv2 ----------------
__global__ __launch_bounds__(256) void conv2_kernel() {
  __shared__ __align__(16) float fe[136][4];
  __shared__ int jn[136];
  __shared__ __align__(16) float h2s[8*SLOTS*CH];
  const int tid = threadIdx.x;
  const int c = tid & 31;
  const int node0 = blockIdx.x << 3;
  float w2aL_c[4], w2b_c[32];
  #pragma unroll
  for (int f = 0; f < 4; ++f)  w2aL_c[f] = g_wts[OW2A + (CH + f)*CH + c];
  #pragma unroll
  for (int k = 0; k < 32; ++k) w2b_c[k] = g_wts[OW2B + k*CH + c];
  const float b2a_c = g_wts[OB2A + c], b2b_c = g_wts[OB2B + c];

  if (tid < 136) {
    int ns = tid / 17, slot = tid - ns*17;
    int i = node0 + ns;
    int j = (slot < KK) ? g_nbr[i*KK + slot] : i;
    jn[tid] = j;
    ppf4(g_pos4[i], g_nrm4[i], g_pos4[j], g_nrm4[j], fe[tid]);
  }
  __syncthreads();
  #pragma unroll
  for (int it = 0; it < 17; ++it) {
    int idx = it*256 + tid;
    int e = idx >> 5;
    float4 f4 = *(const float4*)fe[e];
    float uv = g_u[jn[e]*CH + c];             // x_j @ w2a[0:32] precomputed
    float h = b2a_c + uv + f4.x*w2aL_c[0] + f4.y*w2aL_c[1] + f4.z*w2aL_c[2] + f4.w*w2aL_c[3];
    h2s[idx] = fmaxf(h, 0.f);
  }
  __syncthreads();
  const int ns = tid >> 5;
  float acc = -BIG;
  #pragma unroll
  for (int slot = 0; slot < SLOTS; ++slot) {
    const float* hr = &h2s[(ns*SLOTS + slot)*CH];
    float msg = b2b_c;
    #pragma unroll
    for (int k4 = 0; k4 < 8; ++k4) {
      float4 h4 = *(const float4*)(hr + 4*k4);
      msg += h4.x*w2b_c[4*k4] + h4.y*w2b_c[4*k4+1] + h4.z*w2b_c[4*k4+2] + h4.w*w2b_c[4*k4+3];
    }
    acc = fmaxf(acc, msg);
  }
  g_x2[(node0 + ns)*CH + c] = fmaxf(acc, 0.f);
}

// ---------------- pool + head (float32 output) ----------------
__global__ __launch_bounds__(256) void pool_kernel(float* __restrict__ out) {
  __shared__ float red[8][CH];
  const int g = blockIdx.x;
  const int c = threadIdx.x & 31, chunk = threadIdx.x >> 5;
  const float* base = g_x2 + (size_t)(g*NN + chunk*512)*CH + c;
  float mx = -BIG;
  for (int n = 0; n < 512; ++n) mx = fmaxf(mx, base[n*CH]);
  red[chunk][c] = mx;
  __syncthreads();
  if (threadIdx.x < CH) {
    float m2 = red[0][c];
    #pragma unroll
    for (int r = 1; r < 8; ++r) m2 = fmaxf(m2, red[r][c]);
    red[0][c] = m2;
  }
  __syncthreads();
  if (threadIdx.x < NCLS) {
    int co = threadIdx.x;
    float s = g_wts[OBC + co];
    #pragma unroll
    for (int f = 0; f < CH; ++f) s += red[0][f] * g_wts[OWC + f*NCLS + co];
    out[g*NCLS + co] = s;                     // float32 out (reference dtype)
  }
}

extern "C" void kernel_launch(void* const* d_in, const int* in_sizes, int n_in,
                              void* d_out, int out_size, void* d_ws, size_t ws_size,
                              hipStream_t stream) {
  const void* pos = d_in[0];
  const void* nrm = d_in[1];
  // d_in[2] = batch (int32) -- unused, batches are uniform
  const void* w1a = d_in[3];
  const void* b1a = d_in[4];
  const void* w1b = d_in[5];
  const void* b1b = d_in[6];
  const void* w2a = d_in[7];
  const void* b2a = d_in[8];
  const void* w2b = d_in[9];
  const void* b2b = d_in[10];
  const void* wc  = d_in[11];
  const void* bc  = d_in[12];

  wprep_kernel<<<1,      256, 0, stream>>>(nrm, w1a, b1a, w1b, b1b, w2a, b2a, w2b, b2b, wc, bc);
  prep_kernel <<<MM/256, 256, 0, stream>>>(pos, nrm);
  knn_kernel  <<<MM/4,   256, 0, stream>>>();
  conv1_kernel<<<MM/8,   256, 0, stream>>>();
  conv2_kernel<<<MM/8,   256, 0, stream>>>();
  pool_kernel <<<NB,     256, 0, stream>>>((float*)d_out);
}

// Round 8
// 438.368 us; speedup vs baseline: 1.0138x; 1.0138x over previous
//
#include <hip/hip_runtime.h>
#include <hip/hip_bf16.h>
#include <math.h>

#define NB 8
#define NN 4096
#define KK 16
#define MM (NB*NN)
#define CH 32
#define SLOTS 17
#define NCLS 40
#define BIG 3.0e38f
#define CAP 324   // survivor capacity; P(overflow) ~ e-8 per query

// Weight table offsets (floats)
#define OW1A 0
#define OB1A 128
#define OW1B 160
#define OB1B 1184
#define OW2A 1216
#define OB2A 2368
#define OW2B 2400
#define OB2B 3424
#define OWC  3456
#define OBC  4736
#define NWTS 4776

// Module-global scratch (~11 MB): no assumptions about ws_size.
__device__ float4 g_pos4[MM];
__device__ float4 g_nrm4[MM];
__device__ int    g_nbr[MM*KK];
__device__ float  g_u[MM*CH];
__device__ float  g_x2[MM*CH];
__device__ float  g_wts[NWTS];
__device__ int    g_isf32;

__device__ __forceinline__ float bf(const __hip_bfloat16 x) { return __bfloat162float(x); }

// dual-dtype load: element i of array that is either float32 or bf16
__device__ __forceinline__ float ldf(const void* p, int i, bool f32) {
  return f32 ? ((const float*)p)[i] : bf(((const __hip_bfloat16*)p)[i]);
}

__device__ __forceinline__ float angf(float ax, float ay, float az,
                                      float bx, float by, float bz) {
  float cx = ay*bz - az*by;
  float cy = az*bx - ax*bz;
  float cz = ax*by - ay*bx;
  float s  = cx*cx + cy*cy + cz*cz;
  float cn = s > 0.f ? sqrtf(s) : 0.f;
  float d  = ax*bx + ay*by + az*bz;
  return (cn > 0.f || d != 0.f) ? atan2f(cn, d) : 0.f;
}

__device__ __forceinline__ void ppf4(const float4 pi, const float4 ni,
                                     const float4 pj, const float4 nj, float* f) {
  float px = pj.x - pi.x, py = pj.y - pi.y, pz = pj.z - pi.z;
  float s = px*px + py*py + pz*pz;
  f[0] = s > 0.f ? sqrtf(s) : 0.f;
  f[1] = angf(ni.x, ni.y, ni.z, px, py, pz);
  f[2] = angf(nj.x, nj.y, nj.z, px, py, pz);
  f[3] = angf(ni.x, ni.y, ni.z, nj.x, nj.y, nj.z);
}

// ---------------- wprep: parallel dtype vote + convert weights to fp32 ----------------
__global__ __launch_bounds__(256) void wprep_kernel(
    const void* nrm, const void* w1a, const void* b1a, const void* w1b,
    const void* b1b, const void* w2a, const void* b2a, const void* w2b,
    const void* b2b, const void* wc, const void* bc) {
  __shared__ int sflag;
  const int tid = threadIdx.x;
  if (tid < 64) {
    const float* nf = (const float*)nrm;
    const __hip_bfloat16* nh = (const __hip_bfloat16*)nrm;
    float x = nf[3*tid], y = nf[3*tid+1], z = nf[3*tid+2];
    float ss = x*x + y*y + z*z;
    bool okf = (ss > 0.98f && ss < 1.02f);
    float a = bf(nh[3*tid]), b2 = bf(nh[3*tid+1]), c2 = bf(nh[3*tid+2]);
    float sb = a*a + b2*b2 + c2*c2;
    bool okb = (sb > 0.95f && sb < 1.05f);
    unsigned long long mf = __ballot(okf), mb = __ballot(okb);
    if (tid == 0) {
      sflag = (__popcll(mf) >= __popcll(mb)) ? 1 : 0;
      g_isf32 = sflag;
    }
  }
  __syncthreads();
  const bool f32 = sflag != 0;
  for (int i = tid; i < 128;  i += 256) g_wts[OW1A + i] = ldf(w1a, i, f32);
  for (int i = tid; i < 32;   i += 256) g_wts[OB1A + i] = ldf(b1a, i, f32);
  for (int i = tid; i < 1024; i += 256) g_wts[OW1B + i] = ldf(w1b, i, f32);
  for (int i = tid; i < 32;   i += 256) g_wts[OB1B + i] = ldf(b1b, i, f32);
  for (int i = tid; i < 1152; i += 256) g_wts[OW2A + i] = ldf(w2a, i, f32);
  for (int i = tid; i < 32;   i += 256) g_wts[OB2A + i] = ldf(b2a, i, f32);
  for (int i = tid; i < 1024; i += 256) g_wts[OW2B + i] = ldf(w2b, i, f32);
  for (int i = tid; i < 32;   i += 256) g_wts[OB2B + i] = ldf(b2b, i, f32);
  for (int i = tid; i < 1280; i += 256) g_wts[OWC  + i] = ldf(wc,  i, f32);
  for (int i = tid; i < 40;   i += 256) g_wts[OBC  + i] = ldf(bc,  i, f32);
}

// ---------------- prep: inputs -> float4 (pos.w = |p|^2 f32, filter only) ----------------
__global__ __launch_bounds__(256) void prep_kernel(const void* __restrict__ pos,
                                                   const void* __restrict__ nrm) {
  const bool f32 = g_isf32 != 0;
  int i = blockIdx.x*256 + threadIdx.x;
  float x = ldf(pos, 3*i, f32), y = ldf(pos, 3*i+1, f32), z = ldf(pos, 3*i+2, f32);
  float sq = x*x + y*y + z*z;
  g_pos4[i] = make_float4(x, y, z, sq);
  float a = ldf(nrm, 3*i, f32), b = ldf(nrm, 3*i+1, f32), c = ldf(nrm, 3*i+2, f32);
  g_nrm4[i] = make_float4(a, b, c, 0.f);
}

// ---------------- kNN: one wave per point, two-pass recompute (no d2 register cache) ----
// Pass 1 streams all 4096 candidates computing only the 16 residue-class mins
// (class = lane&15); T = max over classes => >=16 distinct candidates <= T.
// Tf = T + absolute margin (absorbs f32 error AND any FMA-contraction delta
// between the two passes). Pass 2 re-stages tiles, recomputes d2, collects
// survivors (~54) via sparse per-wave LDS atomicAdd. Then f64 rescore
// (numpy-exact association) and exact lexicographic (d2_f64, idx) ranking.
// No d2c[64] array => no AGPR parking => ~50 VGPR => occupancy LDS-limited
// at 5 blocks/CU (20 waves) instead of register-limited at ~12.
__global__ __launch_bounds__(256) void knn_kernel() {
  __shared__ float4 tile[1024];        // 16384 B
  __shared__ int    ilst[4][CAP];      //  5184 B
  __shared__ double dlst[4][CAP];      // 10368 B
  __shared__ int    cnt[4];
  const int tid  = threadIdx.x;
  const int w    = tid >> 6, lane = tid & 63;
  const int blk  = blockIdx.x;
  const int b    = blk >> 10;                 // 1024 blocks per batch
  const int pib  = ((blk & 1023) << 2) | w;   // point-in-batch
  const float4* bp = g_pos4 + b*NN;
  const float4 me = bp[pib];

  // ---- pass 1: class-min only (two chains for ILP) ----
  float lmin0 = BIG, lmin1 = BIG;
  for (int t = 0; t < 4; ++t) {
    #pragma unroll
    for (int k = 0; k < 4; ++k) tile[k*256 + tid] = bp[t*1024 + k*256 + tid];
    __syncthreads();
    #pragma unroll
    for (int r = 0; r < 16; ++r) {
      float4 o  = tile[r*64 + lane];
      int cand  = t*1024 + r*64 + lane;
      float dt  = me.x*o.x + me.y*o.y + me.z*o.z;
      float d2  = (me.w + o.w) - 2.f*dt;
      d2 = (cand == pib) ? BIG : d2;           // exclude self
      if (r & 1) lmin1 = fminf(lmin1, d2); else lmin0 = fminf(lmin0, d2);
    }
    __syncthreads();
  }
  float lmin = fminf(lmin0, lmin1);
  // class = lane&15; merge lanes sharing a class (each class = 256 candidates)
  lmin = fminf(lmin, __shfl_xor(lmin, 16));
  lmin = fminf(lmin, __shfl_xor(lmin, 32));
  float T = lmin;
  #pragma unroll
  for (int d = 1; d < 64; d <<= 1) T = fmaxf(T, __shfl_xor(T, d));
  const float Tf = T + 2e-5f + 1e-5f*fabsf(T);  // absolute margin >> f32 d2 error

  if (lane == 0) cnt[w] = 0;                    // wave-private counter

  // ---- pass 2: recompute + sparse atomic collect ----
  for (int t = 0; t < 4; ++t) {
    #pragma unroll
    for (int k = 0; k < 4; ++k) tile[k*256 + tid] = bp[t*1024 + k*256 + tid];
    __syncthreads();
    #pragma unroll
    for (int r = 0; r < 16; ++r) {
      float4 o  = tile[r*64 + lane];
      int cand  = t*1024 + r*64 + lane;
      float dt  = me.x*o.x + me.y*o.y + me.z*o.z;
      float d2  = (me.w + o.w) - 2.f*dt;
      d2 = (cand == pib) ? BIG : d2;
      if (d2 <= Tf) {
        int p = atomicAdd(&cnt[w], 1);
        if (p < CAP) ilst[w][p] = cand;
      }
    }
    __syncthreads();
  }
  const int m = min(cnt[w], CAP);               // own-wave LDS ops are ordered

  // ---- f64 re-score of survivors, numpy-exact association ----
  const double mx = (double)me.x, my_ = (double)me.y, mz = (double)me.z;
  const double sqme = (mx*mx + my_*my_) + mz*mz;
  for (int e = lane; e < m; e += 64) {
    int ci = ilst[w][e];
    float4 o = bp[ci];
    double ox = (double)o.x, oy = (double)o.y, oz = (double)o.z;
    double sqo = (ox*ox + oy*oy) + oz*oz;
    double dt  = (mx*ox + my_*oy) + mz*oz;
    dlst[w][e] = (sqme + sqo) - 2.0*dt;
  }
  __syncthreads();
  for (int e = lane; e < m; e += 64) {
    double myd = dlst[w][e];
    int myi = ilst[w][e];
    int rank = 0;
    for (int o = 0; o < m; ++o) {            // broadcast LDS reads
      double od = dlst[w][o];
      int oi = ilst[w][o];
      rank += (od < myd) || (od == myd && oi < myi);
    }
    if (rank < KK) g_nbr[(b*NN + pib)*KK + rank] = b*NN + myi;
  }
}

// ---------------- conv1: 8 nodes/block, fused u = relu(max(msg1)) @ w2a[0:32] ----------------
__global__ __launch_bounds__(256) void conv1_kernel() {
  __shared__ __align__(16) float fe[136][4];
  __shared__ __align__(16) float h1s[8*SLOTS*CH];
  __shared__ __align__(16) float xs[8][CH];
  const int tid = threadIdx.x;
  const int c = tid & 31;
  const int node0 = blockIdx.x << 3;
  float w1a_c[4], w1b_c[32], w2a_c[32];
  #pragma unroll
  for (int f = 0; f < 4; ++f)  w1a_c[f] = g_wts[OW1A + f*CH + c];
  #pragma unroll
  for (int k = 0; k < 32; ++k) w1b_c[k] = g_wts[OW1B + k*CH + c];
  #pragma unroll
  for (int k = 0; k < 32; ++k) w2a_c[k] = g_wts[OW2A + k*CH + c];
  const float b1a_c = g_wts[OB1A + c], b1b_c = g_wts[OB1B + c];

  if (tid < 136) {
    int ns = tid / 17, slot = tid - ns*17;
    int i = node0 + ns;
    int j = (slot < KK) ? g_nbr[i*KK + slot] : i;   // slot 16 = self-loop
    ppf4(g_pos4[i], g_nrm4[i], g_pos4[j], g_nrm4[j], fe[tid]);
  }
  __syncthreads();
  #pragma unroll
  for (int it = 0; it < 17; ++it) {
    int idx = it*256 + tid;                   // (e, c) with c == tid&31
    int e = idx >> 5;
    float4 f4 = *(const float4*)fe[e];
    float h = b1a_c + f4.x*w1a_c[0] + f4.y*w1a_c[1] + f4.z*w1a_c[2] + f4.w*w1a_c[3];
    h1s[idx] = fmaxf(h, 0.f);
  }
  __syncthreads();
  const int ns = tid >> 5;
  const int i  = node0 + ns;
  float acc = -BIG;
  #pragma unroll
  for (int slot = 0; slot < SLOTS; ++slot) {
    const float* hr = &h1s[(ns*SLOTS + slot)*CH];
    float msg = b1b_c;
    #pragma unroll
    for (int k4 = 0; k4 < 8; ++k4) {
      float4 h4 = *(const float4*)(hr + 4*k4);
      msg += h4.x*w1b_c[4*k4] + h4.y*w1b_c[4*k4+1] + h4.z*w1b_c[4*k4+2] + h4.w*w1b_c[4*k4+3];
    }
    acc = fmaxf(acc, msg);
  }
  xs[ns][c] = fmaxf(acc, 0.f);                // x1 = relu(segment_max)
  __syncthreads();
  float uu = 0.f;
  #pragma unroll
  for (int k4 = 0; k4 < 8; ++k4) {
    float4 x4 = *(const float4*)&xs[ns][4*k4];
    uu += x4.x*w2a_c[4*k4] + x4.y*w2a_c[4*k4+1] + x4.z*w2a_c[4*k4+2] + x4.w*w2a_c[4*k4+3];
  }
  g_u[i*CH + c] = uu;                         // u = x1 @ w2a[0:32,:]
}

// ---------------- conv2 ----------------
__global__ __launch_bounds__(256) void conv2_kernel() {
  __shared__ __align__(16) float fe[136][4];
  __shared__ int jn[136];
  __shared__ __align__(16) float h2s[8*SLOTS*CH];
  const int tid = threadIdx.x;
  const int c = tid & 31;
  const int node0 = blockIdx.x << 3;
  float w2aL_c[4], w2b_c[32];
  #pragma unroll
  for (int f = 0; f < 4; ++f)  w2aL_c[f] = g_wts[OW2A + (CH + f)*CH + c];
  #pragma unroll
  for (int k = 0; k < 32; ++k) w2b_c[k] = g_wts[OW2B + k*CH + c];
  const float b2a_c = g_wts[OB2A + c], b2b_c = g_wts[OB2B + c];

  if (tid < 136) {
    int ns = tid / 17, slot = tid - ns*17;
    int i = node0 + ns;
    int j = (slot < KK) ? g_nbr[i*KK + slot] : i;
    jn[tid] = j;
    ppf4(g_pos4[i], g_nrm4[i], g_pos4[j], g_nrm4[j], fe[tid]);
  }
  __syncthreads();
  #pragma unroll
  for (int it = 0; it < 17; ++it) {
    int idx = it*256 + tid;
    int e = idx >> 5;
    float4 f4 = *(const float4*)fe[e];
    float uv = g_u[jn[e]*CH + c];             // x_j @ w2a[0:32] precomputed
    float h = b2a_c + uv + f4.x*w2aL_c[0] + f4.y*w2aL_c[1] + f4.z*w2aL_c[2] + f4.w*w2aL_c[3];
    h2s[idx] = fmaxf(h, 0.f);
  }
  __syncthreads();
  const int ns = tid >> 5;
  float acc = -BIG;
  #pragma unroll
  for (int slot = 0; slot < SLOTS; ++slot) {
    const float* hr = &h2s[(ns*SLOTS + slot)*CH];
    float msg = b2b_c;
    #pragma unroll
    for (int k4 = 0; k4 < 8; ++k4) {
      float4 h4 = *(const float4*)(hr + 4*k4);
      msg += h4.x*w2b_c[4*k4] + h4.y*w2b_c[4*k4+1] + h4.z*w2b_c[4*k4+2] + h4.w*w2b_c[4*k4+3];
    }
    acc = fmaxf(acc, msg);
  }
  g_x2[(node0 + ns)*CH + c] = fmaxf(acc, 0.f);
}

// ---------------- pool + head (float32 output) ----------------
__global__ __launch_bounds__(256) void pool_kernel(float* __restrict__ out) {
  __shared__ float red[8][CH];
  const int g = blockIdx.x;
  const int c = threadIdx.x & 31, chunk = threadIdx.x >> 5;
  const float* base = g_x2 + (size_t)(g*NN + chunk*512)*CH + c;
  float mx = -BIG;
  for (int n = 0; n < 512; ++n) mx = fmaxf(mx, base[n*CH]);
  red[chunk][c] = mx;
  __syncthreads();
  if (threadIdx.x < CH) {
    float m2 = red[0][c];
    #pragma unroll
    for (int r = 1; r < 8; ++r) m2 = fmaxf(m2, red[r][c]);
    red[0][c] = m2;
  }
  __syncthreads();
  if (threadIdx.x < NCLS) {
    int co = threadIdx.x;
    float s = g_wts[OBC + co];
    #pragma unroll
    for (int f = 0; f < CH; ++f) s += red[0][f] * g_wts[OWC + f*NCLS + co];
    out[g*NCLS + co] = s;                     // float32 out (reference dtype)
  }
}

extern "C" void kernel_launch(void* const* d_in, const int* in_sizes, int n_in,
                              void* d_out, int out_size, void* d_ws, size_t ws_size,
                              hipStream_t stream) {
  const void* pos = d_in[0];
  const void* nrm = d_in[1];
  // d_in[2] = batch (int32) -- unused, batches are uniform
  const void* w1a = d_in[3];
  const void* b1a = d_in[4];
  const void* w1b = d_in[5];
  const void* b1b = d_in[6];
  const void* w2a = d_in[7];
  const void* b2a = d_in[8];
  const void* w2b = d_in[9];
  const void* b2b = d_in[10];
  const void* wc  = d_in[11];
  const void* bc  = d_in[12];

  wprep_kernel<<<1,      256, 0, stream>>>(nrm, w1a, b1a, w1b, b1b, w2a, b2a, w2b, b2b, wc, bc);
  prep_kernel <<<MM/256, 256, 0, stream>>>(pos, nrm);
  knn_kernel  <<<MM/4,   256, 0, stream>>>();
  conv1_kernel<<<MM/8,   256, 0, stream>>>();
  conv2_kernel<<<MM/8,   256, 0, stream>>>();
  pool_kernel <<<NB,     256, 0, stream>>>((float*)d_out);
}